// Round 3
// baseline (441.740 us; speedup 1.0000x reference)
//
#include <hip/hip_runtime.h>

typedef unsigned int u32;

#define JAX_PARTITIONABLE 1

// ---------- Threefry-2x32, 20 rounds (matches jax._src.prng.threefry2x32) ----
__host__ __device__ static inline void tf2x32(u32 k0, u32 k1, u32 x0, u32 x1,
                                              u32* o0, u32* o1)
{
  const u32 ks2 = k0 ^ k1 ^ 0x1BD11BDAu;
#define TF_R(v, r) (((v) << (r)) | ((v) >> (32 - (r))))
#define TF_RND(r) do { x0 += x1; x1 = TF_R(x1, r); x1 ^= x0; } while (0);
  x0 += k0; x1 += k1;
  TF_RND(13) TF_RND(15) TF_RND(26) TF_RND(6)
  x0 += k1;  x1 += ks2 + 1u;
  TF_RND(17) TF_RND(29) TF_RND(16) TF_RND(24)
  x0 += ks2; x1 += k0 + 2u;
  TF_RND(13) TF_RND(15) TF_RND(26) TF_RND(6)
  x0 += k0;  x1 += k1 + 3u;
  TF_RND(17) TF_RND(29) TF_RND(16) TF_RND(24)
  x0 += k1;  x1 += ks2 + 4u;
  TF_RND(13) TF_RND(15) TF_RND(26) TF_RND(6)
  x0 += ks2; x1 += k0 + 5u;
  *o0 = x0; *o1 = x1;
#undef TF_RND
#undef TF_R
}

// ---------- K0: x = q @ W_in (seq-d fma chain), rates, gate probs -----------
__global__ __launch_bounds__(64) void k_gate(
    const float* __restrict__ q, const float* __restrict__ win,
    const float* __restrict__ gbias, const float* __restrict__ temp,
    const float* __restrict__ gk, float* __restrict__ rates,
    float* __restrict__ gateo)
{
  const int b = blockIdx.x, j = threadIdx.x;
  __shared__ float xs[64];
  const float* __restrict__ qr = q + b * 1024;   // qr[d] uniform -> s_load
  float c = 0.f;
  for (int d = 0; d < 1024; ++d)
    c = __builtin_fmaf(qr[d], win[d * 64 + j], c);
  const float x = c;
  float r;
  if (x >= 0.f) r = __fdiv_rn(1.f, __fadd_rn(1.f, expf(-x)));
  else { const float ex = expf(x); r = __fdiv_rn(ex, __fadd_rn(1.f, ex)); }
  rates[b * 64 + j] = r;
  xs[j] = x;
  __syncthreads();
  if (j < 16) {
    float l = 0.f;
    for (int d = 0; d < 64; ++d)
      l = __builtin_fmaf(xs[d], gk[d * 16 + j], l);
    l = __fadd_rn(l, gbias[j]);
    l = __fdiv_rn(l, temp[0]);
    float m = l;
    for (int off = 1; off < 16; off <<= 1) m = fmaxf(m, __shfl_xor(m, off, 16));
    const float p = expf(__fsub_rn(l, m));
    float s = p;
    for (int off = 1; off < 16; off <<= 1) s += __shfl_xor(s, off, 16);
    gateo[b * 16 + j] = __fdiv_rn(p, s);
  }
}

// ---------- K1: Poisson spikes via threefry -> f32 0/1, layout [T][B][D] -----
__global__ __launch_bounds__(256) void k_spikes(
    const float* __restrict__ rates, float* __restrict__ spkf, u32 bk0, u32 bk1)
{
  const u32 g = blockIdx.x * 256u + threadIdx.x;
#if JAX_PARTITIONABLE
  u32 o0, o1;
  tf2x32(bk0, bk1, 0u, g, &o0, &o1);            // 64-bit counter (0, g)
  const u32 bits = o0 ^ o1;
  const float r = rates[g & 16383u];
  const float u = __uint_as_float((bits >> 9) | 0x3f800000u) - 1.0f;
  spkf[g] = (u < r) ? 1.0f : 0.0f;
#else
  u32 o0, o1;
  tf2x32(bk0, bk1, g, g + 163840u, &o0, &o1);
  const float r = rates[g & 16383u];
  const float ua = __uint_as_float((o0 >> 9) | 0x3f800000u) - 1.0f;
  const float ub = __uint_as_float((o1 >> 9) | 0x3f800000u) - 1.0f;
  spkf[g] = (ua < r) ? 1.0f : 0.0f;
  spkf[g + 163840u] = (ub < r) ? 1.0f : 0.0f;
#endif
}

// ---------- K2: bit-exact LIF scan (register-resident weights, 4 b-chains) --
// thread <-> (e, h); 64 weight f32 pinned in VGPRs (asm "+v" forbids remat);
// 4 batches per thread = 4 independent fma chains (VALU issue-bound);
// spike rows wave-uniform -> s_load, SGPR operand into v_fmac.
// All fp ops in exact np order (verified passing round 2).
// grid (4 h-chunks, 64 b-groups, 16 e), 256 thr.
__global__ __launch_bounds__(256) void k_lif(
    const float* __restrict__ spkf, const float* __restrict__ w,
    unsigned char* __restrict__ cnt)
{
  const int e = blockIdx.z;
  const int h = blockIdx.x * 256 + threadIdx.x;
  const int b0 = blockIdx.y * 4;

  float wr[64];
  const float* __restrict__ wb = w + (size_t)e * 65536 + h;
#pragma unroll
  for (int d = 0; d < 64; ++d) {
    wr[d] = wb[d * 1024];
    asm volatile("" : "+v"(wr[d]));   // pin in VGPR: forbid remat/reload
  }

  float v0 = 0.f, v1 = 0.f, v2 = 0.f, v3 = 0.f;
  int c0 = 0, c1 = 0, c2 = 0, c3 = 0;

  for (int t = 0; t < 20; ++t) {
    const float* __restrict__ r0 = spkf + (size_t)(t * 256 + b0) * 64;
    float a0 = 0.f, a1 = 0.f, a2 = 0.f, a3 = 0.f;
#pragma unroll
    for (int d = 0; d < 64; ++d) {
      a0 = __builtin_fmaf(r0[d], wr[d], a0);
      a1 = __builtin_fmaf(r0[64 + d], wr[d], a1);
      a2 = __builtin_fmaf(r0[128 + d], wr[d], a2);
      a3 = __builtin_fmaf(r0[192 + d], wr[d], a3);
    }
    // np: t1 = current - v; t2 = t1 * leak; new_v = v + t2  (3 roundings)
    float nv;
    nv = __fadd_rn(v0, __fmul_rn(__fsub_rn(a0, v0), 0.05f));
    if (nv >= 0.5f) { c0++; v0 = 0.f; } else v0 = nv;
    nv = __fadd_rn(v1, __fmul_rn(__fsub_rn(a1, v1), 0.05f));
    if (nv >= 0.5f) { c1++; v1 = 0.f; } else v1 = nv;
    nv = __fadd_rn(v2, __fmul_rn(__fsub_rn(a2, v2), 0.05f));
    if (nv >= 0.5f) { c2++; v2 = 0.f; } else v2 = nv;
    nv = __fadd_rn(v3, __fmul_rn(__fsub_rn(a3, v3), 0.05f));
    if (nv >= 0.5f) { c3++; v3 = 0.f; } else v3 = nv;
  }

  unsigned char* cb = cnt + ((size_t)e * 256 + b0) * 1024 + h;
  cb[0] = (unsigned char)c0;
  cb[1024] = (unsigned char)c1;
  cb[2048] = (unsigned char)c2;
  cb[3072] = (unsigned char)c3;
}

// ---------- K3: out[b,h] = ascending-e fma chain of (cnt/20)*p --------------
__global__ __launch_bounds__(256) void k_combine(
    const unsigned char* __restrict__ cnt, const float* __restrict__ gateo,
    float* __restrict__ out)
{
  const int idx = blockIdx.x * 256 + threadIdx.x;
  const int b = idx >> 10, h = idx & 1023;
  float s = 0.f;
#pragma unroll
  for (int e = 0; e < 16; ++e) {
    const float av = __fdiv_rn((float)cnt[((size_t)e * 256 + b) * 1024 + h], 20.f);
    s = __builtin_fmaf(av, gateo[b * 16 + e], s);
  }
  out[idx] = s;
}

// ---------- launch ----------------------------------------------------------
extern "C" void kernel_launch(void* const* d_in, const int* in_sizes, int n_in,
                              void* d_out, int out_size, void* d_ws, size_t ws_size,
                              hipStream_t stream)
{
  (void)in_sizes; (void)n_in; (void)out_size; (void)ws_size;
  const float* q     = (const float*)d_in[0];
  const float* gbias = (const float*)d_in[1];
  const float* temp  = (const float*)d_in[2];
  const float* win   = (const float*)d_in[3];
  const float* ex    = (const float*)d_in[4];
  const float* gk    = (const float*)d_in[5];
  float* out = (float*)d_out;

  char* ws = (char*)d_ws;
  float* spkf  = (float*)(ws + 0);          // [20][256][64] f32   1310720 B
  float* rates = (float*)(ws + 1310720);    // [256][64] f32         65536 B
  float* gateo = (float*)(ws + 1376256);    // [256][16] f32         16384 B
  unsigned char* cnt = (unsigned char*)(ws + 1392640); // [16][256][1024] u8 4194304 B
                                            // total: 5586944 B

  // bern_key = jax.random.split(jax.random.key(0))[1], computed on host
  u32 bk0, bk1;
#if JAX_PARTITIONABLE
  tf2x32(0u, 0u, 0u, 1u, &bk0, &bk1);
#else
  u32 a0o, a1o, b0o, b1o;
  tf2x32(0u, 0u, 0u, 2u, &a0o, &a1o);
  tf2x32(0u, 0u, 1u, 3u, &b0o, &b1o);
  bk0 = a1o; bk1 = b1o;
#endif

  k_gate<<<256, 64, 0, stream>>>(q, win, gbias, temp, gk, rates, gateo);
#if JAX_PARTITIONABLE
  k_spikes<<<1280, 256, 0, stream>>>(rates, spkf, bk0, bk1);
#else
  k_spikes<<<640, 256, 0, stream>>>(rates, spkf, bk0, bk1);
#endif
  k_lif<<<dim3(4, 64, 16), 256, 0, stream>>>(spkf, ex, cnt);
  k_combine<<<1024, 256, 0, stream>>>(cnt, gateo, out);
}

// Round 4
// 233.427 us; speedup vs baseline: 1.8924x; 1.8924x over previous
//
#include <hip/hip_runtime.h>

typedef unsigned int u32;
typedef unsigned short u16;
typedef unsigned char u8;
typedef __attribute__((ext_vector_type(8))) short bf16x8;
typedef __attribute__((ext_vector_type(4))) float f32x4;

#define JAX_PARTITIONABLE 1
#define FLAG_DELTA 5e-4f
#define FLAG_CAP 262144u

// ---------- Threefry-2x32, 20 rounds (matches jax._src.prng.threefry2x32) ----
__host__ __device__ static inline void tf2x32(u32 k0, u32 k1, u32 x0, u32 x1,
                                              u32* o0, u32* o1)
{
  const u32 ks2 = k0 ^ k1 ^ 0x1BD11BDAu;
#define TF_R(v, r) (((v) << (r)) | ((v) >> (32 - (r))))
#define TF_RND(r) do { x0 += x1; x1 = TF_R(x1, r); x1 ^= x0; } while (0);
  x0 += k0; x1 += k1;
  TF_RND(13) TF_RND(15) TF_RND(26) TF_RND(6)
  x0 += k1;  x1 += ks2 + 1u;
  TF_RND(17) TF_RND(29) TF_RND(16) TF_RND(24)
  x0 += ks2; x1 += k0 + 2u;
  TF_RND(13) TF_RND(15) TF_RND(26) TF_RND(6)
  x0 += k0;  x1 += k1 + 3u;
  TF_RND(17) TF_RND(29) TF_RND(16) TF_RND(24)
  x0 += k1;  x1 += ks2 + 4u;
  TF_RND(13) TF_RND(15) TF_RND(26) TF_RND(6)
  x0 += ks2; x1 += k0 + 5u;
  *o0 = x0; *o1 = x1;
#undef TF_RND
#undef TF_R
}

__device__ static inline u16 f2bf(float f) {
  u32 u = __float_as_uint(f);
  return (u16)((u + 0x7FFFu + ((u >> 16) & 1u)) >> 16);
}
__device__ static inline float bf2f(u16 b) {
  return __uint_as_float(((u32)b) << 16);
}

// ---------- K0: x = q @ W_in (seq-d fma chain), rates, gate probs -----------
// (verified passing round 2; also zeroes the flag counter)
__global__ __launch_bounds__(64) void k_gate(
    const float* __restrict__ q, const float* __restrict__ win,
    const float* __restrict__ gbias, const float* __restrict__ temp,
    const float* __restrict__ gk, float* __restrict__ rates,
    float* __restrict__ gateo, u32* __restrict__ fcnt)
{
  const int b = blockIdx.x, j = threadIdx.x;
  if (b == 0 && j == 0) fcnt[0] = 0;
  __shared__ float xs[64];
  const float* __restrict__ qr = q + b * 1024;
  float c = 0.f;
  for (int d = 0; d < 1024; ++d)
    c = __builtin_fmaf(qr[d], win[d * 64 + j], c);
  const float x = c;
  float r;
  if (x >= 0.f) r = __fdiv_rn(1.f, __fadd_rn(1.f, expf(-x)));
  else { const float ex = expf(x); r = __fdiv_rn(ex, __fadd_rn(1.f, ex)); }
  rates[b * 64 + j] = r;
  xs[j] = x;
  __syncthreads();
  if (j < 16) {
    float l = 0.f;
    for (int d = 0; d < 64; ++d)
      l = __builtin_fmaf(xs[d], gk[d * 16 + j], l);
    l = __fadd_rn(l, gbias[j]);
    l = __fdiv_rn(l, temp[0]);
    float m = l;
    for (int off = 1; off < 16; off <<= 1) m = fmaxf(m, __shfl_xor(m, off, 16));
    const float p = expf(__fsub_rn(l, m));
    float s = p;
    for (int off = 1; off < 16; off <<= 1) s += __shfl_xor(s, off, 16);
    gateo[b * 16 + j] = __fdiv_rn(p, s);
  }
}

// ---------- K0b: experts [E][D][H] f32 -> (W*leak) split hi/lo bf16 [E][H][D]
__global__ __launch_bounds__(256) void k_split(
    const float* __restrict__ ex, u16* __restrict__ wsp)
{
  const int e = blockIdx.x >> 4, hb = blockIdx.x & 15;
  const int tl = threadIdx.x & 63, tg = threadIdx.x >> 6;
  __shared__ float tile[64][65];
#pragma unroll
  for (int r = 0; r < 16; ++r) {
    const int d = r * 4 + tg;
    tile[d][tl] = ex[((size_t)e * 64 + d) * 1024 + hb * 64 + tl];
  }
  __syncthreads();
#pragma unroll
  for (int r = 0; r < 16; ++r) {
    const int hl = r * 4 + tg;
    const float wv = tile[tl][hl] * 0.05f;           // fold leak = DT/TAU
    const u16 hi = f2bf(wv);
    const u16 lo = f2bf(wv - bf2f(hi));
    const size_t o = ((size_t)e * 1024 + hb * 64 + hl) * 64 + tl;
    wsp[o] = hi;
    wsp[o + 1048576] = lo;
  }
}

// ---------- K1: Poisson spikes via threefry -> bf16 0/1, layout [T][B][D] ----
// (PRNG stream verified passing round 2)
__global__ __launch_bounds__(256) void k_spikes(
    const float* __restrict__ rates, u16* __restrict__ spk, u32 bk0, u32 bk1)
{
  const u32 g = blockIdx.x * 256u + threadIdx.x;
#if JAX_PARTITIONABLE
  u32 o0, o1;
  tf2x32(bk0, bk1, 0u, g, &o0, &o1);
  const u32 bits = o0 ^ o1;
  const float r = rates[g & 16383u];
  const float u = __uint_as_float((bits >> 9) | 0x3f800000u) - 1.0f;
  spk[g] = (u < r) ? (u16)0x3F80 : (u16)0;
#else
  u32 o0, o1;
  tf2x32(bk0, bk1, g, g + 163840u, &o0, &o1);
  const float r = rates[g & 16383u];
  const float ua = __uint_as_float((o0 >> 9) | 0x3f800000u) - 1.0f;
  const float ub = __uint_as_float((o1 >> 9) | 0x3f800000u) - 1.0f;
  spk[g] = (ua < r) ? (u16)0x3F80 : (u16)0;
  spk[g + 163840u] = (ub < r) ? (u16)0x3F80 : (u16)0;
#endif
}

// ---------- K2: approx LIF scan via bf16-split MFMA + borderline flagging ----
// wave tile 16b x 64h; B-frags in regs; per-element flag if any step has
// |nv - 0.5| < FLAG_DELTA (drift bound: worst ~1.5e-4, typ ~1e-5).
// grid (8 hblk, 8 bblk, 16 e), 256 thr = 4 waves.
__global__ __launch_bounds__(256) void k_lif(
    const u16* __restrict__ spk, const u16* __restrict__ wsp,
    u8* __restrict__ cnt, u32* __restrict__ fcnt, u32* __restrict__ flist)
{
  const int hblk = blockIdx.x, bblk = blockIdx.y, e = blockIdx.z;
  const int tid = threadIdx.x;
  const int w = tid >> 6, lane = tid & 63;
  const int wb = w & 1, wh = w >> 1;
  const int lr = lane & 15, lg = lane >> 4;
  const int b0 = bblk * 32 + wb * 16;
  const int h0 = hblk * 128 + wh * 64;

  // B frags: wsp[e][h][d]; lane: n = lr (h), k = kc*32 + lg*8 + j
  bf16x8 bf[4][2][2];
#pragma unroll
  for (int nt = 0; nt < 4; ++nt)
#pragma unroll
    for (int kc = 0; kc < 2; ++kc)
#pragma unroll
      for (int s = 0; s < 2; ++s)
        bf[nt][kc][s] = *(const bf16x8*)(wsp +
            ((size_t)((s * 16 + e) * 1024 + h0 + nt * 16 + lr)) * 64 + kc * 32 + lg * 8);

  f32x4 v[4];
  int cn[4][4];
  u32 fl = 0;
#pragma unroll
  for (int nt = 0; nt < 4; ++nt) {
    v[nt] = (f32x4){0.f, 0.f, 0.f, 0.f};
#pragma unroll
    for (int i = 0; i < 4; ++i) cn[nt][i] = 0;
  }

  const u16* abase = spk + (size_t)(b0 + lr) * 64 + lg * 8;
#pragma unroll 2
  for (int t = 0; t < 20; ++t) {
    const bf16x8 a0 = *(const bf16x8*)(abase + (size_t)t * 16384);
    const bf16x8 a1 = *(const bf16x8*)(abase + (size_t)t * 16384 + 32);
#pragma unroll
    for (int nt = 0; nt < 4; ++nt) {
      f32x4 acc = v[nt] * 0.95f;         // 0.95*v + sum s*(0.05*w)
      acc = __builtin_amdgcn_mfma_f32_16x16x32_bf16(a0, bf[nt][0][0], acc, 0, 0, 0);
      acc = __builtin_amdgcn_mfma_f32_16x16x32_bf16(a1, bf[nt][1][0], acc, 0, 0, 0);
      acc = __builtin_amdgcn_mfma_f32_16x16x32_bf16(a0, bf[nt][0][1], acc, 0, 0, 0);
      acc = __builtin_amdgcn_mfma_f32_16x16x32_bf16(a1, bf[nt][1][1], acc, 0, 0, 0);
#pragma unroll
      for (int i = 0; i < 4; ++i) {
        float nv = (i == 0) ? acc.x : (i == 1) ? acc.y : (i == 2) ? acc.z : acc.w;
        const float tt = nv - 0.5f;
        if (__builtin_fabsf(tt) < FLAG_DELTA) fl |= (1u << (nt * 4 + i));
        const bool sp = (tt >= 0.f);
        cn[nt][i] += sp;
        nv = sp ? 0.f : nv;
        if (i == 0) acc.x = nv; else if (i == 1) acc.y = nv;
        else if (i == 2) acc.z = nv; else acc.w = nv;
      }
      v[nt] = acc;
    }
  }

  // C/D layout: col = lane&15 (h), row = (lane>>4)*4 + reg (b)
#pragma unroll
  for (int nt = 0; nt < 4; ++nt) {
    const int h = h0 + nt * 16 + lr;
#pragma unroll
    for (int i = 0; i < 4; ++i) {
      const int b = b0 + lg * 4 + i;
      cnt[((size_t)e * 256 + b) * 1024 + h] = (u8)cn[nt][i];
    }
  }
  if (fl) {
#pragma unroll
    for (int nt = 0; nt < 4; ++nt)
#pragma unroll
      for (int i = 0; i < 4; ++i)
        if ((fl >> (nt * 4 + i)) & 1u) {
          const u32 slot = atomicAdd(fcnt, 1u);
          if (slot < FLAG_CAP)
            flist[slot] = ((u32)e << 18) | ((u32)(b0 + lg * 4 + i) << 10) |
                          (u32)(h0 + nt * 16 + lr);
        }
  }
}

// ---------- K2b: exact recompute of flagged elements (round-2 math) ---------
__global__ __launch_bounds__(256) void k_fix(
    const u16* __restrict__ spk, const float* __restrict__ exw,
    const u32* __restrict__ fcnt, const u32* __restrict__ flist,
    u8* __restrict__ cnt)
{
  u32 n = fcnt[0];
  if (n > FLAG_CAP) n = FLAG_CAP;
  for (u32 i = blockIdx.x * 256u + threadIdx.x; i < n; i += 65536u) {
    const u32 p = flist[i];
    const int h = (int)(p & 1023u), b = (int)((p >> 10) & 255u), e = (int)(p >> 18);
    const float* __restrict__ wbp = exw + (size_t)e * 65536 + h;
    float wr[64];
#pragma unroll
    for (int d = 0; d < 64; ++d) wr[d] = wbp[d * 1024];
    float v = 0.f;
    int c = 0;
    for (int t = 0; t < 20; ++t) {
      const u16* __restrict__ sr = spk + (size_t)(t * 256 + b) * 64;
      float cc = 0.f;
#pragma unroll
      for (int d = 0; d < 64; ++d) {
        const float sv = __uint_as_float(((u32)sr[d]) << 16);  // exact 0/1
        cc = __builtin_fmaf(sv, wr[d], cc);
      }
      // np: new_v = v + (current - v)*leak  (3 roundings, exact order)
      const float nv = __fadd_rn(v, __fmul_rn(__fsub_rn(cc, v), 0.05f));
      if (nv >= 0.5f) { c++; v = 0.f; } else v = nv;
    }
    cnt[((size_t)e * 256 + b) * 1024 + h] = (u8)c;
  }
}

// ---------- K3: out[b,h] = ascending-e fma chain of (cnt/20)*p --------------
__global__ __launch_bounds__(256) void k_combine(
    const u8* __restrict__ cnt, const float* __restrict__ gateo,
    float* __restrict__ out)
{
  const int idx = blockIdx.x * 256 + threadIdx.x;
  const int b = idx >> 10, h = idx & 1023;
  float s = 0.f;
#pragma unroll
  for (int e = 0; e < 16; ++e) {
    const float av = __fdiv_rn((float)cnt[((size_t)e * 256 + b) * 1024 + h], 20.f);
    s = __builtin_fmaf(av, gateo[b * 16 + e], s);
  }
  out[idx] = s;
}

// ---------- launch ----------------------------------------------------------
extern "C" void kernel_launch(void* const* d_in, const int* in_sizes, int n_in,
                              void* d_out, int out_size, void* d_ws, size_t ws_size,
                              hipStream_t stream)
{
  (void)in_sizes; (void)n_in; (void)out_size; (void)ws_size;
  const float* q     = (const float*)d_in[0];
  const float* gbias = (const float*)d_in[1];
  const float* temp  = (const float*)d_in[2];
  const float* win   = (const float*)d_in[3];
  const float* ex    = (const float*)d_in[4];
  const float* gk    = (const float*)d_in[5];
  float* out = (float*)d_out;

  char* ws = (char*)d_ws;
  u16*  spk   = (u16*)(ws + 0);            // [20][256][64] bf16    655360 B
  float* rates = (float*)(ws + 655360);    // [256][64] f32          65536 B
  float* gateo = (float*)(ws + 720896);    // [256][16] f32          16384 B
  u16*  wsp   = (u16*)(ws + 737280);       // [2][16][1024][64]    4194304 B
  u8*   cnt   = (u8*)(ws + 4931584);       // [16][256][1024] u8   4194304 B
  u32*  fcnt  = (u32*)(ws + 9125888);      // counter                  4 B
  u32*  flist = (u32*)(ws + 9126912);      // [262144] u32         1048576 B
                                           // total: 10175488 B

  u32 bk0, bk1;
#if JAX_PARTITIONABLE
  tf2x32(0u, 0u, 0u, 1u, &bk0, &bk1);
#else
  u32 a0o, a1o, b0o, b1o;
  tf2x32(0u, 0u, 0u, 2u, &a0o, &a1o);
  tf2x32(0u, 0u, 1u, 3u, &b0o, &b1o);
  bk0 = a1o; bk1 = b1o;
#endif

  k_gate<<<256, 64, 0, stream>>>(q, win, gbias, temp, gk, rates, gateo, fcnt);
  k_split<<<256, 256, 0, stream>>>(ex, wsp);
#if JAX_PARTITIONABLE
  k_spikes<<<1280, 256, 0, stream>>>(rates, spk, bk0, bk1);
#else
  k_spikes<<<640, 256, 0, stream>>>(rates, spk, bk0, bk1);
#endif
  k_lif<<<dim3(8, 8, 16), 256, 0, stream>>>(spk, wsp, cnt, fcnt, flist);
  k_fix<<<256, 256, 0, stream>>>(spk, ex, fcnt, flist, cnt);
  k_combine<<<1024, 256, 0, stream>>>(cnt, gateo, out);
}

// Round 5
// 229.008 us; speedup vs baseline: 1.9289x; 1.0193x over previous
//
#include <hip/hip_runtime.h>

typedef unsigned int u32;
typedef unsigned short u16;
typedef unsigned char u8;
typedef __attribute__((ext_vector_type(8))) short bf16x8;
typedef __attribute__((ext_vector_type(4))) float f32x4;

#define JAX_PARTITIONABLE 1
#define FLAG_DELTA 5e-4f
#define FLAG_CAP 262144u

// ---------- Threefry-2x32, 20 rounds (matches jax._src.prng.threefry2x32) ----
__host__ __device__ static inline void tf2x32(u32 k0, u32 k1, u32 x0, u32 x1,
                                              u32* o0, u32* o1)
{
  const u32 ks2 = k0 ^ k1 ^ 0x1BD11BDAu;
#define TF_R(v, r) (((v) << (r)) | ((v) >> (32 - (r))))
#define TF_RND(r) do { x0 += x1; x1 = TF_R(x1, r); x1 ^= x0; } while (0);
  x0 += k0; x1 += k1;
  TF_RND(13) TF_RND(15) TF_RND(26) TF_RND(6)
  x0 += k1;  x1 += ks2 + 1u;
  TF_RND(17) TF_RND(29) TF_RND(16) TF_RND(24)
  x0 += ks2; x1 += k0 + 2u;
  TF_RND(13) TF_RND(15) TF_RND(26) TF_RND(6)
  x0 += k0;  x1 += k1 + 3u;
  TF_RND(17) TF_RND(29) TF_RND(16) TF_RND(24)
  x0 += k1;  x1 += ks2 + 4u;
  TF_RND(13) TF_RND(15) TF_RND(26) TF_RND(6)
  x0 += ks2; x1 += k0 + 5u;
  *o0 = x0; *o1 = x1;
#undef TF_RND
#undef TF_R
}

__device__ static inline u16 f2bf(float f) {
  u32 u = __float_as_uint(f);
  return (u16)((u + 0x7FFFu + ((u >> 16) & 1u)) >> 16);
}
__device__ static inline float bf2f(u16 b) {
  return __uint_as_float(((u32)b) << 16);
}

// ---------- K0: x = q @ W_in (exact ascending-d chain, pipelined loads) -----
// q row in LDS (broadcast ds_read); win column double-buffered in regs 64-deep
// (chunk loads independent -> one L2 latency round per 64). Chain order and
// every fp op identical to the round-2-verified version.
__global__ __launch_bounds__(64) void k_gate(
    const float* __restrict__ q, const float* __restrict__ win,
    const float* __restrict__ gbias, const float* __restrict__ temp,
    const float* __restrict__ gk, float* __restrict__ rates,
    float* __restrict__ gateo, u32* __restrict__ fcnt)
{
  const int b = blockIdx.x, j = threadIdx.x;
  if (b == 0 && j == 0) fcnt[0] = 0;
  __shared__ float qs[1024];
  __shared__ float xs[64];
  const float* __restrict__ qr = q + b * 1024;
  for (int d = j; d < 1024; d += 64) qs[d] = qr[d];
  __syncthreads();

  const float* __restrict__ wc = win + j;          // this thread's column
  float bufA[64], bufB[64];
#pragma unroll
  for (int i = 0; i < 64; ++i) bufA[i] = wc[i * 64];
  float c = 0.f;
#pragma unroll
  for (int ch = 0; ch < 8; ++ch) {
    // load odd chunk (2ch+1) into B while chaining A
#pragma unroll
    for (int i = 0; i < 64; ++i)
      bufB[i] = wc[((2 * ch + 1) * 64 + i) * 64];
#pragma unroll
    for (int i = 0; i < 64; ++i)
      c = __builtin_fmaf(qs[2 * ch * 64 + i], bufA[i], c);
    if (ch < 7) {
#pragma unroll
      for (int i = 0; i < 64; ++i)
        bufA[i] = wc[((2 * ch + 2) * 64 + i) * 64];
    }
#pragma unroll
    for (int i = 0; i < 64; ++i)
      c = __builtin_fmaf(qs[(2 * ch + 1) * 64 + i], bufB[i], c);
  }
  const float x = c;
  float r;
  if (x >= 0.f) r = __fdiv_rn(1.f, __fadd_rn(1.f, expf(-x)));
  else { const float ex = expf(x); r = __fdiv_rn(ex, __fadd_rn(1.f, ex)); }
  rates[b * 64 + j] = r;
  xs[j] = x;
  __syncthreads();
  if (j < 16) {
    float l = 0.f;
    for (int d = 0; d < 64; ++d)
      l = __builtin_fmaf(xs[d], gk[d * 16 + j], l);
    l = __fadd_rn(l, gbias[j]);
    l = __fdiv_rn(l, temp[0]);
    float m = l;
    for (int off = 1; off < 16; off <<= 1) m = fmaxf(m, __shfl_xor(m, off, 16));
    const float p = expf(__fsub_rn(l, m));
    float s = p;
    for (int off = 1; off < 16; off <<= 1) s += __shfl_xor(s, off, 16);
    gateo[b * 16 + j] = __fdiv_rn(p, s);
  }
}

// ---------- K0b: experts [E][D][H] f32 -> (W*leak) split hi/lo bf16 [E][H][D]
__global__ __launch_bounds__(256) void k_split(
    const float* __restrict__ ex, u16* __restrict__ wsp)
{
  const int e = blockIdx.x >> 4, hb = blockIdx.x & 15;
  const int tl = threadIdx.x & 63, tg = threadIdx.x >> 6;
  __shared__ float tile[64][65];
#pragma unroll
  for (int r = 0; r < 16; ++r) {
    const int d = r * 4 + tg;
    tile[d][tl] = ex[((size_t)e * 64 + d) * 1024 + hb * 64 + tl];
  }
  __syncthreads();
#pragma unroll
  for (int r = 0; r < 16; ++r) {
    const int hl = r * 4 + tg;
    const float wv = tile[tl][hl] * 0.05f;           // fold leak = DT/TAU
    const u16 hi = f2bf(wv);
    const u16 lo = f2bf(wv - bf2f(hi));
    const size_t o = ((size_t)e * 1024 + hb * 64 + hl) * 64 + tl;
    wsp[o] = hi;
    wsp[o + 1048576] = lo;
  }
}

// ---------- K1: Poisson spikes via threefry -> bf16 0/1, layout [T][B][D] ----
__global__ __launch_bounds__(256) void k_spikes(
    const float* __restrict__ rates, u16* __restrict__ spk, u32 bk0, u32 bk1)
{
  const u32 g = blockIdx.x * 256u + threadIdx.x;
#if JAX_PARTITIONABLE
  u32 o0, o1;
  tf2x32(bk0, bk1, 0u, g, &o0, &o1);
  const u32 bits = o0 ^ o1;
  const float r = rates[g & 16383u];
  const float u = __uint_as_float((bits >> 9) | 0x3f800000u) - 1.0f;
  spk[g] = (u < r) ? (u16)0x3F80 : (u16)0;
#else
  u32 o0, o1;
  tf2x32(bk0, bk1, g, g + 163840u, &o0, &o1);
  const float r = rates[g & 16383u];
  const float ua = __uint_as_float((o0 >> 9) | 0x3f800000u) - 1.0f;
  const float ub = __uint_as_float((o1 >> 9) | 0x3f800000u) - 1.0f;
  spk[g] = (ua < r) ? (u16)0x3F80 : (u16)0;
  spk[g + 163840u] = (ub < r) ? (u16)0x3F80 : (u16)0;
#endif
}

// ---------- K2: approx LIF scan, MFMA + flags; latency-optimized ------------
// wave tile 16b x 32h (nt=2) -> 8192 waves; t+1 spikes prefetched into regs;
// hi/lo MFMA chains split (2+2) and merged with 4 adds; VGPR capped 128.
// grid (16 hblk, 8 bblk, 16 e), 256 thr = 4 waves.
__global__ __launch_bounds__(256, 4) void k_lif(
    const u16* __restrict__ spk, const u16* __restrict__ wsp,
    u8* __restrict__ cnt, u32* __restrict__ fcnt, u32* __restrict__ flist)
{
  const int hblk = blockIdx.x, bblk = blockIdx.y, e = blockIdx.z;
  const int tid = threadIdx.x;
  const int w = tid >> 6, lane = tid & 63;
  const int wb = w & 1, wh = w >> 1;
  const int lr = lane & 15, lg = lane >> 4;
  const int b0 = bblk * 32 + wb * 16;
  const int h0 = hblk * 64 + wh * 32;

  // B frags: wsp[s][e][h][d]; lane: n = lr (h), k = kc*32 + lg*8 + j
  bf16x8 bf[2][2][2];
#pragma unroll
  for (int nt = 0; nt < 2; ++nt)
#pragma unroll
    for (int kc = 0; kc < 2; ++kc)
#pragma unroll
      for (int s = 0; s < 2; ++s)
        bf[nt][kc][s] = *(const bf16x8*)(wsp +
            ((size_t)((s * 16 + e) * 1024 + h0 + nt * 16 + lr)) * 64 + kc * 32 + lg * 8);

  f32x4 v[2];
  int cn[2][4];
  u32 fl = 0;
#pragma unroll
  for (int nt = 0; nt < 2; ++nt) {
    v[nt] = (f32x4){0.f, 0.f, 0.f, 0.f};
#pragma unroll
    for (int i = 0; i < 4; ++i) cn[nt][i] = 0;
  }

  const u16* abase = spk + (size_t)(b0 + lr) * 64 + lg * 8;
  bf16x8 a0 = *(const bf16x8*)(abase);
  bf16x8 a1 = *(const bf16x8*)(abase + 32);

#define PROC(VAL, CREF, BIT) {                                  \
    const float tt = (VAL) - 0.5f;                              \
    if (__builtin_fabsf(tt) < FLAG_DELTA) fl |= (1u << (BIT));  \
    const bool sp = (tt >= 0.f);                                \
    (CREF) += sp;                                               \
    (VAL) = sp ? 0.f : (VAL); }

#pragma unroll 2
  for (int t = 0; t < 20; ++t) {
    const int tn = (t < 19) ? t + 1 : 19;          // prefetch next (clamped)
    const bf16x8 n0 = *(const bf16x8*)(abase + (size_t)tn * 16384);
    const bf16x8 n1 = *(const bf16x8*)(abase + (size_t)tn * 16384 + 32);
#pragma unroll
    for (int nt = 0; nt < 2; ++nt) {
      f32x4 accA = v[nt] * 0.95f;                  // hi chain, seeded v*(1-leak)
      accA = __builtin_amdgcn_mfma_f32_16x16x32_bf16(a0, bf[nt][0][0], accA, 0, 0, 0);
      accA = __builtin_amdgcn_mfma_f32_16x16x32_bf16(a1, bf[nt][1][0], accA, 0, 0, 0);
      f32x4 accB = (f32x4){0.f, 0.f, 0.f, 0.f};    // lo chain (tiny terms)
      accB = __builtin_amdgcn_mfma_f32_16x16x32_bf16(a0, bf[nt][0][1], accB, 0, 0, 0);
      accB = __builtin_amdgcn_mfma_f32_16x16x32_bf16(a1, bf[nt][1][1], accB, 0, 0, 0);
      f32x4 nv = accA + accB;                      // merge (4 v_add)
      PROC(nv.x, cn[nt][0], nt * 4 + 0)
      PROC(nv.y, cn[nt][1], nt * 4 + 1)
      PROC(nv.z, cn[nt][2], nt * 4 + 2)
      PROC(nv.w, cn[nt][3], nt * 4 + 3)
      v[nt] = nv;
    }
    a0 = n0; a1 = n1;
  }
#undef PROC

  // C/D layout: col = lane&15 (h), row = (lane>>4)*4 + reg (b)
#pragma unroll
  for (int nt = 0; nt < 2; ++nt) {
    const int h = h0 + nt * 16 + lr;
#pragma unroll
    for (int i = 0; i < 4; ++i) {
      const int b = b0 + lg * 4 + i;
      cnt[((size_t)e * 256 + b) * 1024 + h] = (u8)cn[nt][i];
    }
  }
  if (fl) {
#pragma unroll
    for (int nt = 0; nt < 2; ++nt)
#pragma unroll
      for (int i = 0; i < 4; ++i)
        if ((fl >> (nt * 4 + i)) & 1u) {
          const u32 slot = atomicAdd(fcnt, 1u);
          if (slot < FLAG_CAP)
            flist[slot] = ((u32)e << 18) | ((u32)(b0 + lg * 4 + i) << 10) |
                          (u32)(h0 + nt * 16 + lr);
        }
  }
}

// ---------- K2b: exact recompute of flagged elements (round-2 math) ---------
// spike rows loaded as uint4 (8 loads/t instead of 64), exact bf16 unpack.
__global__ __launch_bounds__(256) void k_fix(
    const u16* __restrict__ spk, const float* __restrict__ exw,
    const u32* __restrict__ fcnt, const u32* __restrict__ flist,
    u8* __restrict__ cnt)
{
  u32 n = fcnt[0];
  if (n > FLAG_CAP) n = FLAG_CAP;
  for (u32 i = blockIdx.x * 256u + threadIdx.x; i < n; i += 65536u) {
    const u32 p = flist[i];
    const int h = (int)(p & 1023u), b = (int)((p >> 10) & 255u), e = (int)(p >> 18);
    const float* __restrict__ wbp = exw + (size_t)e * 65536 + h;
    float wr[64];
#pragma unroll
    for (int d = 0; d < 64; ++d) wr[d] = wbp[d * 1024];
    float v = 0.f;
    int c = 0;
    for (int t = 0; t < 20; ++t) {
      const uint4* __restrict__ sr = (const uint4*)(spk + (size_t)(t * 256 + b) * 64);
      float cc = 0.f;
#pragma unroll
      for (int w8 = 0; w8 < 8; ++w8) {
        const uint4 sv = sr[w8];
        // ascending d: low u16 first (little-endian), exact bf16 decode
        cc = __builtin_fmaf(__uint_as_float(sv.x << 16),         wr[w8 * 8 + 0], cc);
        cc = __builtin_fmaf(__uint_as_float(sv.x & 0xFFFF0000u), wr[w8 * 8 + 1], cc);
        cc = __builtin_fmaf(__uint_as_float(sv.y << 16),         wr[w8 * 8 + 2], cc);
        cc = __builtin_fmaf(__uint_as_float(sv.y & 0xFFFF0000u), wr[w8 * 8 + 3], cc);
        cc = __builtin_fmaf(__uint_as_float(sv.z << 16),         wr[w8 * 8 + 4], cc);
        cc = __builtin_fmaf(__uint_as_float(sv.z & 0xFFFF0000u), wr[w8 * 8 + 5], cc);
        cc = __builtin_fmaf(__uint_as_float(sv.w << 16),         wr[w8 * 8 + 6], cc);
        cc = __builtin_fmaf(__uint_as_float(sv.w & 0xFFFF0000u), wr[w8 * 8 + 7], cc);
      }
      // np: new_v = v + (current - v)*leak  (3 roundings, exact order)
      const float nv = __fadd_rn(v, __fmul_rn(__fsub_rn(cc, v), 0.05f));
      if (nv >= 0.5f) { c++; v = 0.f; } else v = nv;
    }
    cnt[((size_t)e * 256 + b) * 1024 + h] = (u8)c;
  }
}

// ---------- K3: out[b,h] = ascending-e fma chain of (cnt/20)*p --------------
__global__ __launch_bounds__(256) void k_combine(
    const u8* __restrict__ cnt, const float* __restrict__ gateo,
    float* __restrict__ out)
{
  const int idx = blockIdx.x * 256 + threadIdx.x;
  const int b = idx >> 10, h = idx & 1023;
  float s = 0.f;
#pragma unroll
  for (int e = 0; e < 16; ++e) {
    const float av = __fdiv_rn((float)cnt[((size_t)e * 256 + b) * 1024 + h], 20.f);
    s = __builtin_fmaf(av, gateo[b * 16 + e], s);
  }
  out[idx] = s;
}

// ---------- launch ----------------------------------------------------------
extern "C" void kernel_launch(void* const* d_in, const int* in_sizes, int n_in,
                              void* d_out, int out_size, void* d_ws, size_t ws_size,
                              hipStream_t stream)
{
  (void)in_sizes; (void)n_in; (void)out_size; (void)ws_size;
  const float* q     = (const float*)d_in[0];
  const float* gbias = (const float*)d_in[1];
  const float* temp  = (const float*)d_in[2];
  const float* win   = (const float*)d_in[3];
  const float* ex    = (const float*)d_in[4];
  const float* gk    = (const float*)d_in[5];
  float* out = (float*)d_out;

  char* ws = (char*)d_ws;
  u16*  spk   = (u16*)(ws + 0);            // [20][256][64] bf16    655360 B
  float* rates = (float*)(ws + 655360);    // [256][64] f32          65536 B
  float* gateo = (float*)(ws + 720896);    // [256][16] f32          16384 B
  u16*  wsp   = (u16*)(ws + 737280);       // [2][16][1024][64]    4194304 B
  u8*   cnt   = (u8*)(ws + 4931584);       // [16][256][1024] u8   4194304 B
  u32*  fcnt  = (u32*)(ws + 9125888);      // counter                  4 B
  u32*  flist = (u32*)(ws + 9126912);      // [262144] u32         1048576 B
                                           // total: 10175488 B

  u32 bk0, bk1;
#if JAX_PARTITIONABLE
  tf2x32(0u, 0u, 0u, 1u, &bk0, &bk1);
#else
  u32 a0o, a1o, b0o, b1o;
  tf2x32(0u, 0u, 0u, 2u, &a0o, &a1o);
  tf2x32(0u, 0u, 1u, 3u, &b0o, &b1o);
  bk0 = a1o; bk1 = b1o;
#endif

  k_gate<<<256, 64, 0, stream>>>(q, win, gbias, temp, gk, rates, gateo, fcnt);
  k_split<<<256, 256, 0, stream>>>(ex, wsp);
#if JAX_PARTITIONABLE
  k_spikes<<<1280, 256, 0, stream>>>(rates, spk, bk0, bk1);
#else
  k_spikes<<<640, 256, 0, stream>>>(rates, spk, bk0, bk1);
#endif
  k_lif<<<dim3(16, 8, 16), 256, 0, stream>>>(spk, wsp, cnt, fcnt, flist);
  k_fix<<<256, 256, 0, stream>>>(spk, ex, fcnt, flist, cnt);
  k_combine<<<1024, 256, 0, stream>>>(cnt, gateo, out);
}

// Round 6
// 216.259 us; speedup vs baseline: 2.0426x; 1.0590x over previous
//
#include <hip/hip_runtime.h>

typedef unsigned int u32;
typedef unsigned short u16;
typedef unsigned char u8;
typedef __attribute__((ext_vector_type(8))) short bf16x8;
typedef __attribute__((ext_vector_type(4))) float f32x4;

#define JAX_PARTITIONABLE 1
#define FLAG_DELTA 5e-4f
#define FLAG_CAP 262144u

// ---------- Threefry-2x32, 20 rounds (matches jax._src.prng.threefry2x32) ----
__host__ __device__ static inline void tf2x32(u32 k0, u32 k1, u32 x0, u32 x1,
                                              u32* o0, u32* o1)
{
  const u32 ks2 = k0 ^ k1 ^ 0x1BD11BDAu;
#define TF_R(v, r) (((v) << (r)) | ((v) >> (32 - (r))))
#define TF_RND(r) do { x0 += x1; x1 = TF_R(x1, r); x1 ^= x0; } while (0);
  x0 += k0; x1 += k1;
  TF_RND(13) TF_RND(15) TF_RND(26) TF_RND(6)
  x0 += k1;  x1 += ks2 + 1u;
  TF_RND(17) TF_RND(29) TF_RND(16) TF_RND(24)
  x0 += ks2; x1 += k0 + 2u;
  TF_RND(13) TF_RND(15) TF_RND(26) TF_RND(6)
  x0 += k0;  x1 += k1 + 3u;
  TF_RND(17) TF_RND(29) TF_RND(16) TF_RND(24)
  x0 += k1;  x1 += ks2 + 4u;
  TF_RND(13) TF_RND(15) TF_RND(26) TF_RND(6)
  x0 += ks2; x1 += k0 + 5u;
  *o0 = x0; *o1 = x1;
#undef TF_RND
#undef TF_R
}

__device__ static inline u16 f2bf(float f) {
  u32 u = __float_as_uint(f);
  return (u16)((u + 0x7FFFu + ((u >> 16) & 1u)) >> 16);
}
__device__ static inline float bf2f(u16 b) {
  return __uint_as_float(((u32)b) << 16);
}

// ---------- K0: x = q @ W_in (exact ascending-d chain, pipelined loads) -----
__global__ __launch_bounds__(64) void k_gate(
    const float* __restrict__ q, const float* __restrict__ win,
    const float* __restrict__ gbias, const float* __restrict__ temp,
    const float* __restrict__ gk, float* __restrict__ rates,
    float* __restrict__ gateo, u32* __restrict__ fcnt)
{
  const int b = blockIdx.x, j = threadIdx.x;
  if (b == 0 && j == 0) fcnt[0] = 0;
  __shared__ float qs[1024];
  __shared__ float xs[64];
  const float* __restrict__ qr = q + b * 1024;
  for (int d = j; d < 1024; d += 64) qs[d] = qr[d];
  __syncthreads();

  const float* __restrict__ wc = win + j;
  float bufA[64], bufB[64];
#pragma unroll
  for (int i = 0; i < 64; ++i) bufA[i] = wc[i * 64];
  float c = 0.f;
#pragma unroll
  for (int ch = 0; ch < 8; ++ch) {
#pragma unroll
    for (int i = 0; i < 64; ++i)
      bufB[i] = wc[((2 * ch + 1) * 64 + i) * 64];
#pragma unroll
    for (int i = 0; i < 64; ++i)
      c = __builtin_fmaf(qs[2 * ch * 64 + i], bufA[i], c);
    if (ch < 7) {
#pragma unroll
      for (int i = 0; i < 64; ++i)
        bufA[i] = wc[((2 * ch + 2) * 64 + i) * 64];
    }
#pragma unroll
    for (int i = 0; i < 64; ++i)
      c = __builtin_fmaf(qs[(2 * ch + 1) * 64 + i], bufB[i], c);
  }
  const float x = c;
  float r;
  if (x >= 0.f) r = __fdiv_rn(1.f, __fadd_rn(1.f, expf(-x)));
  else { const float ex = expf(x); r = __fdiv_rn(ex, __fadd_rn(1.f, ex)); }
  rates[b * 64 + j] = r;
  xs[j] = x;
  __syncthreads();
  if (j < 16) {
    float l = 0.f;
    for (int d = 0; d < 64; ++d)
      l = __builtin_fmaf(xs[d], gk[d * 16 + j], l);
    l = __fadd_rn(l, gbias[j]);
    l = __fdiv_rn(l, temp[0]);
    float m = l;
    for (int off = 1; off < 16; off <<= 1) m = fmaxf(m, __shfl_xor(m, off, 16));
    const float p = expf(__fsub_rn(l, m));
    float s = p;
    for (int off = 1; off < 16; off <<= 1) s += __shfl_xor(s, off, 16);
    gateo[b * 16 + j] = __fdiv_rn(p, s);
  }
}

// ---------- K1: fused {expert split | poisson spikes} (independent work) -----
// blocks [0,256): experts [E][D][H] f32 -> (W*leak) hi/lo bf16 [E][H][D]
// blocks [256,...): threefry spikes -> bf16 0/1, layout [T][B][D]
__global__ __launch_bounds__(256) void k_prep(
    const float* __restrict__ ex, u16* __restrict__ wsp,
    const float* __restrict__ rates, u16* __restrict__ spk, u32 bk0, u32 bk1)
{
  if (blockIdx.x < 256) {
    const int e = blockIdx.x >> 4, hb = blockIdx.x & 15;
    const int tl = threadIdx.x & 63, tg = threadIdx.x >> 6;
    __shared__ float tile[64][65];
#pragma unroll
    for (int r = 0; r < 16; ++r) {
      const int d = r * 4 + tg;
      tile[d][tl] = ex[((size_t)e * 64 + d) * 1024 + hb * 64 + tl];
    }
    __syncthreads();
#pragma unroll
    for (int r = 0; r < 16; ++r) {
      const int hl = r * 4 + tg;
      const float wv = tile[tl][hl] * 0.05f;         // fold leak = DT/TAU
      const u16 hi = f2bf(wv);
      const u16 lo = f2bf(wv - bf2f(hi));
      const size_t o = ((size_t)e * 1024 + hb * 64 + hl) * 64 + tl;
      wsp[o] = hi;
      wsp[o + 1048576] = lo;
    }
  } else {
    const u32 g = (blockIdx.x - 256) * 256u + threadIdx.x;
#if JAX_PARTITIONABLE
    u32 o0, o1;
    tf2x32(bk0, bk1, 0u, g, &o0, &o1);
    const u32 bits = o0 ^ o1;
    const float r = rates[g & 16383u];
    const float u = __uint_as_float((bits >> 9) | 0x3f800000u) - 1.0f;
    spk[g] = (u < r) ? (u16)0x3F80 : (u16)0;
#else
    u32 o0, o1;
    tf2x32(bk0, bk1, g, g + 163840u, &o0, &o1);
    const float r = rates[g & 16383u];
    const float ua = __uint_as_float((o0 >> 9) | 0x3f800000u) - 1.0f;
    const float ub = __uint_as_float((o1 >> 9) | 0x3f800000u) - 1.0f;
    spk[g] = (ua < r) ? (u16)0x3F80 : (u16)0;
    spk[g + 163840u] = (ub < r) ? (u16)0x3F80 : (u16)0;
#endif
  }
}

// ---------- K2: approx LIF scan, MFMA + flags -------------------------------
// wave tile 16b x 64h (nt=4); weight frags asm-pinned in VGPRs (64 regs) so
// the compiler CANNOT sink the loads into the t-loop (R4/R5 pathology:
// VGPR_Count 48-88 proved frags were reloaded from L2 every step).
// t+1 spikes prefetched; hi/lo 2+2 MFMA chains merged (R5-verified math).
// grid (8 hblk, 8 bblk, 16 e), 256 thr = 4 waves; 3 waves/SIMD resident.
__global__ __launch_bounds__(256, 3) void k_lif(
    const u16* __restrict__ spk, const u16* __restrict__ wsp,
    u8* __restrict__ cnt, u32* __restrict__ fcnt, u32* __restrict__ flist)
{
  const int hblk = blockIdx.x, bblk = blockIdx.y, e = blockIdx.z;
  const int tid = threadIdx.x;
  const int w = tid >> 6, lane = tid & 63;
  const int wb = w & 1, wh = w >> 1;
  const int lr = lane & 15, lg = lane >> 4;
  const int b0 = bblk * 32 + wb * 16;
  const int h0 = hblk * 128 + wh * 64;

  // B frags: wsp[s][e][h][d]; lane: n = lr (h), k = kc*32 + lg*8 + j
  bf16x8 bf[4][2][2];
#pragma unroll
  for (int nt = 0; nt < 4; ++nt)
#pragma unroll
    for (int kc = 0; kc < 2; ++kc)
#pragma unroll
      for (int s = 0; s < 2; ++s)
        bf[nt][kc][s] = *(const bf16x8*)(wsp +
            ((size_t)((s * 16 + e) * 1024 + h0 + nt * 16 + lr)) * 64 + kc * 32 + lg * 8);
  // Pin all 16 frags (64 VGPRs) as opaque asm results: forbids remat/reload.
#pragma unroll
  for (int nt = 0; nt < 4; ++nt)
#pragma unroll
    for (int kc = 0; kc < 2; ++kc)
#pragma unroll
      for (int s = 0; s < 2; ++s)
        asm volatile("" : "+v"(bf[nt][kc][s]));

  f32x4 v[4];
  int cn[4][4];
  u32 fl = 0;
#pragma unroll
  for (int nt = 0; nt < 4; ++nt) {
    v[nt] = (f32x4){0.f, 0.f, 0.f, 0.f};
#pragma unroll
    for (int i = 0; i < 4; ++i) cn[nt][i] = 0;
  }

  const u16* abase = spk + (size_t)(b0 + lr) * 64 + lg * 8;
  bf16x8 a0 = *(const bf16x8*)(abase);
  bf16x8 a1 = *(const bf16x8*)(abase + 32);

#define PROC(VAL, CREF, BIT) {                                  \
    const float tt = (VAL) - 0.5f;                              \
    if (__builtin_fabsf(tt) < FLAG_DELTA) fl |= (1u << (BIT));  \
    const bool sp = (tt >= 0.f);                                \
    (CREF) += sp;                                               \
    (VAL) = sp ? 0.f : (VAL); }

  for (int t = 0; t < 20; ++t) {
    const int tn = (t < 19) ? t + 1 : 19;          // prefetch next (clamped)
    const bf16x8 n0 = *(const bf16x8*)(abase + (size_t)tn * 16384);
    const bf16x8 n1 = *(const bf16x8*)(abase + (size_t)tn * 16384 + 32);
#pragma unroll
    for (int nt = 0; nt < 4; ++nt) {
      f32x4 accA = v[nt] * 0.95f;                  // hi chain, seeded v*(1-leak)
      accA = __builtin_amdgcn_mfma_f32_16x16x32_bf16(a0, bf[nt][0][0], accA, 0, 0, 0);
      accA = __builtin_amdgcn_mfma_f32_16x16x32_bf16(a1, bf[nt][1][0], accA, 0, 0, 0);
      f32x4 accB = (f32x4){0.f, 0.f, 0.f, 0.f};    // lo chain (tiny terms)
      accB = __builtin_amdgcn_mfma_f32_16x16x32_bf16(a0, bf[nt][0][1], accB, 0, 0, 0);
      accB = __builtin_amdgcn_mfma_f32_16x16x32_bf16(a1, bf[nt][1][1], accB, 0, 0, 0);
      f32x4 nv = accA + accB;                      // merge (4 v_add)
      PROC(nv.x, cn[nt][0], nt * 4 + 0)
      PROC(nv.y, cn[nt][1], nt * 4 + 1)
      PROC(nv.z, cn[nt][2], nt * 4 + 2)
      PROC(nv.w, cn[nt][3], nt * 4 + 3)
      v[nt] = nv;
    }
    a0 = n0; a1 = n1;
  }
#undef PROC

  // C/D layout: col = lane&15 (h), row = (lane>>4)*4 + reg (b)
#pragma unroll
  for (int nt = 0; nt < 4; ++nt) {
    const int h = h0 + nt * 16 + lr;
#pragma unroll
    for (int i = 0; i < 4; ++i) {
      const int b = b0 + lg * 4 + i;
      cnt[((size_t)e * 256 + b) * 1024 + h] = (u8)cn[nt][i];
    }
  }
  if (fl) {
#pragma unroll
    for (int nt = 0; nt < 4; ++nt)
#pragma unroll
      for (int i = 0; i < 4; ++i)
        if ((fl >> (nt * 4 + i)) & 1u) {
          const u32 slot = atomicAdd(fcnt, 1u);
          if (slot < FLAG_CAP)
            flist[slot] = ((u32)e << 18) | ((u32)(b0 + lg * 4 + i) << 10) |
                          (u32)(h0 + nt * 16 + lr);
        }
  }
}

// ---------- K2b: exact recompute of flagged elements (round-2 math) ---------
__global__ __launch_bounds__(256) void k_fix(
    const u16* __restrict__ spk, const float* __restrict__ exw,
    const u32* __restrict__ fcnt, const u32* __restrict__ flist,
    u8* __restrict__ cnt)
{
  u32 n = fcnt[0];
  if (n > FLAG_CAP) n = FLAG_CAP;
  for (u32 i = blockIdx.x * 256u + threadIdx.x; i < n; i += 65536u) {
    const u32 p = flist[i];
    const int h = (int)(p & 1023u), b = (int)((p >> 10) & 255u), e = (int)(p >> 18);
    const float* __restrict__ wbp = exw + (size_t)e * 65536 + h;
    float wr[64];
#pragma unroll
    for (int d = 0; d < 64; ++d) wr[d] = wbp[d * 1024];
    float v = 0.f;
    int c = 0;
    for (int t = 0; t < 20; ++t) {
      const uint4* __restrict__ sr = (const uint4*)(spk + (size_t)(t * 256 + b) * 64);
      float cc = 0.f;
#pragma unroll
      for (int w8 = 0; w8 < 8; ++w8) {
        const uint4 sv = sr[w8];
        cc = __builtin_fmaf(__uint_as_float(sv.x << 16),         wr[w8 * 8 + 0], cc);
        cc = __builtin_fmaf(__uint_as_float(sv.x & 0xFFFF0000u), wr[w8 * 8 + 1], cc);
        cc = __builtin_fmaf(__uint_as_float(sv.y << 16),         wr[w8 * 8 + 2], cc);
        cc = __builtin_fmaf(__uint_as_float(sv.y & 0xFFFF0000u), wr[w8 * 8 + 3], cc);
        cc = __builtin_fmaf(__uint_as_float(sv.z << 16),         wr[w8 * 8 + 4], cc);
        cc = __builtin_fmaf(__uint_as_float(sv.z & 0xFFFF0000u), wr[w8 * 8 + 5], cc);
        cc = __builtin_fmaf(__uint_as_float(sv.w << 16),         wr[w8 * 8 + 6], cc);
        cc = __builtin_fmaf(__uint_as_float(sv.w & 0xFFFF0000u), wr[w8 * 8 + 7], cc);
      }
      const float nv = __fadd_rn(v, __fmul_rn(__fsub_rn(cc, v), 0.05f));
      if (nv >= 0.5f) { c++; v = 0.f; } else v = nv;
    }
    cnt[((size_t)e * 256 + b) * 1024 + h] = (u8)c;
  }
}

// ---------- K3: out[b,h] = ascending-e fma chain of (cnt/20)*p --------------
__global__ __launch_bounds__(256) void k_combine(
    const u8* __restrict__ cnt, const float* __restrict__ gateo,
    float* __restrict__ out)
{
  const int idx = blockIdx.x * 256 + threadIdx.x;
  const int b = idx >> 10, h = idx & 1023;
  float s = 0.f;
#pragma unroll
  for (int e = 0; e < 16; ++e) {
    const float av = __fdiv_rn((float)cnt[((size_t)e * 256 + b) * 1024 + h], 20.f);
    s = __builtin_fmaf(av, gateo[b * 16 + e], s);
  }
  out[idx] = s;
}

// ---------- launch ----------------------------------------------------------
extern "C" void kernel_launch(void* const* d_in, const int* in_sizes, int n_in,
                              void* d_out, int out_size, void* d_ws, size_t ws_size,
                              hipStream_t stream)
{
  (void)in_sizes; (void)n_in; (void)out_size; (void)ws_size;
  const float* q     = (const float*)d_in[0];
  const float* gbias = (const float*)d_in[1];
  const float* temp  = (const float*)d_in[2];
  const float* win   = (const float*)d_in[3];
  const float* ex    = (const float*)d_in[4];
  const float* gk    = (const float*)d_in[5];
  float* out = (float*)d_out;

  char* ws = (char*)d_ws;
  u16*  spk   = (u16*)(ws + 0);            // [20][256][64] bf16    655360 B
  float* rates = (float*)(ws + 655360);    // [256][64] f32          65536 B
  float* gateo = (float*)(ws + 720896);    // [256][16] f32          16384 B
  u16*  wsp   = (u16*)(ws + 737280);       // [2][16][1024][64]    4194304 B
  u8*   cnt   = (u8*)(ws + 4931584);       // [16][256][1024] u8   4194304 B
  u32*  fcnt  = (u32*)(ws + 9125888);      // counter                  4 B
  u32*  flist = (u32*)(ws + 9126912);      // [262144] u32         1048576 B
                                           // total: 10175488 B

  u32 bk0, bk1;
#if JAX_PARTITIONABLE
  tf2x32(0u, 0u, 0u, 1u, &bk0, &bk1);
#else
  u32 a0o, a1o, b0o, b1o;
  tf2x32(0u, 0u, 0u, 2u, &a0o, &a1o);
  tf2x32(0u, 0u, 1u, 3u, &b0o, &b1o);
  bk0 = a1o; bk1 = b1o;
#endif

  k_gate<<<256, 64, 0, stream>>>(q, win, gbias, temp, gk, rates, gateo, fcnt);
#if JAX_PARTITIONABLE
  k_prep<<<256 + 1280, 256, 0, stream>>>(ex, wsp, rates, spk, bk0, bk1);
#else
  k_prep<<<256 + 640, 256, 0, stream>>>(ex, wsp, rates, spk, bk0, bk1);
#endif
  k_lif<<<dim3(8, 8, 16), 256, 0, stream>>>(spk, wsp, cnt, fcnt, flist);
  k_fix<<<256, 256, 0, stream>>>(spk, ex, fcnt, flist, cnt);
  k_combine<<<1024, 256, 0, stream>>>(cnt, gateo, out);
}

// Round 7
// 166.744 us; speedup vs baseline: 2.6492x; 1.2970x over previous
//
#include <hip/hip_runtime.h>

typedef unsigned int u32;
typedef unsigned short u16;
typedef unsigned char u8;
typedef __attribute__((ext_vector_type(8))) short bf16x8;
typedef __attribute__((ext_vector_type(4))) float f32x4;

#define JAX_PARTITIONABLE 1
#define FLAG_DELTA 5e-4f
#define FLAG_CAP 262144u

// ---------- Threefry-2x32, 20 rounds (matches jax._src.prng.threefry2x32) ----
__host__ __device__ static inline void tf2x32(u32 k0, u32 k1, u32 x0, u32 x1,
                                              u32* o0, u32* o1)
{
  const u32 ks2 = k0 ^ k1 ^ 0x1BD11BDAu;
#define TF_R(v, r) (((v) << (r)) | ((v) >> (32 - (r))))
#define TF_RND(r) do { x0 += x1; x1 = TF_R(x1, r); x1 ^= x0; } while (0);
  x0 += k0; x1 += k1;
  TF_RND(13) TF_RND(15) TF_RND(26) TF_RND(6)
  x0 += k1;  x1 += ks2 + 1u;
  TF_RND(17) TF_RND(29) TF_RND(16) TF_RND(24)
  x0 += ks2; x1 += k0 + 2u;
  TF_RND(13) TF_RND(15) TF_RND(26) TF_RND(6)
  x0 += k0;  x1 += k1 + 3u;
  TF_RND(17) TF_RND(29) TF_RND(16) TF_RND(24)
  x0 += k1;  x1 += ks2 + 4u;
  TF_RND(13) TF_RND(15) TF_RND(26) TF_RND(6)
  x0 += ks2; x1 += k0 + 5u;
  *o0 = x0; *o1 = x1;
#undef TF_RND
#undef TF_R
}

__device__ static inline u16 f2bf(float f) {
  u32 u = __float_as_uint(f);
  return (u16)((u + 0x7FFFu + ((u >> 16) & 1u)) >> 16);
}
__device__ static inline float bf2f(u16 b) {
  return __uint_as_float(((u32)b) << 16);
}

// ---------- K0: x = q @ W_in (exact ascending-d chain, pipelined loads) -----
__global__ __launch_bounds__(64) void k_gate(
    const float* __restrict__ q, const float* __restrict__ win,
    const float* __restrict__ gbias, const float* __restrict__ temp,
    const float* __restrict__ gk, float* __restrict__ rates,
    float* __restrict__ gateo, u32* __restrict__ fcnt)
{
  const int b = blockIdx.x, j = threadIdx.x;
  if (b == 0 && j == 0) fcnt[0] = 0;
  __shared__ float qs[1024];
  __shared__ float xs[64];
  const float* __restrict__ qr = q + b * 1024;
  for (int d = j; d < 1024; d += 64) qs[d] = qr[d];
  __syncthreads();

  const float* __restrict__ wc = win + j;
  float bufA[64], bufB[64];
#pragma unroll
  for (int i = 0; i < 64; ++i) bufA[i] = wc[i * 64];
  float c = 0.f;
#pragma unroll
  for (int ch = 0; ch < 8; ++ch) {
#pragma unroll
    for (int i = 0; i < 64; ++i)
      bufB[i] = wc[((2 * ch + 1) * 64 + i) * 64];
#pragma unroll
    for (int i = 0; i < 64; ++i)
      c = __builtin_fmaf(qs[2 * ch * 64 + i], bufA[i], c);
    if (ch < 7) {
#pragma unroll
      for (int i = 0; i < 64; ++i)
        bufA[i] = wc[((2 * ch + 2) * 64 + i) * 64];
    }
#pragma unroll
    for (int i = 0; i < 64; ++i)
      c = __builtin_fmaf(qs[(2 * ch + 1) * 64 + i], bufB[i], c);
  }
  const float x = c;
  float r;
  if (x >= 0.f) r = __fdiv_rn(1.f, __fadd_rn(1.f, expf(-x)));
  else { const float ex = expf(x); r = __fdiv_rn(ex, __fadd_rn(1.f, ex)); }
  rates[b * 64 + j] = r;
  xs[j] = x;
  __syncthreads();
  if (j < 16) {
    float l = 0.f;
    for (int d = 0; d < 64; ++d)
      l = __builtin_fmaf(xs[d], gk[d * 16 + j], l);
    l = __fadd_rn(l, gbias[j]);
    l = __fdiv_rn(l, temp[0]);
    float m = l;
    for (int off = 1; off < 16; off <<= 1) m = fmaxf(m, __shfl_xor(m, off, 16));
    const float p = expf(__fsub_rn(l, m));
    float s = p;
    for (int off = 1; off < 16; off <<= 1) s += __shfl_xor(s, off, 16);
    gateo[b * 16 + j] = __fdiv_rn(p, s);
  }
}

// ---------- K1: fused {expert split+transpose | poisson spikes} --------------
// blocks [0,256): experts [E][D][H] f32 -> (W*leak) hi/lo bf16 [E][H][D]
//                 AND raw f32 transpose ext[E][H][D] (for k_fix coalescing)
// blocks [256,...): threefry spikes -> bf16 0/1, layout [T][B][D]
__global__ __launch_bounds__(256) void k_prep(
    const float* __restrict__ ex, u16* __restrict__ wsp, float* __restrict__ ext,
    const float* __restrict__ rates, u16* __restrict__ spk, u32 bk0, u32 bk1)
{
  if (blockIdx.x < 256) {
    const int e = blockIdx.x >> 4, hb = blockIdx.x & 15;
    const int tl = threadIdx.x & 63, tg = threadIdx.x >> 6;
    __shared__ float tile[64][65];
#pragma unroll
    for (int r = 0; r < 16; ++r) {
      const int d = r * 4 + tg;
      tile[d][tl] = ex[((size_t)e * 64 + d) * 1024 + hb * 64 + tl];
    }
    __syncthreads();
#pragma unroll
    for (int r = 0; r < 16; ++r) {
      const int hl = r * 4 + tg;
      const float wraw = tile[tl][hl];
      const float wv = wraw * 0.05f;                 // fold leak = DT/TAU
      const u16 hi = f2bf(wv);
      const u16 lo = f2bf(wv - bf2f(hi));
      const size_t o = ((size_t)e * 1024 + hb * 64 + hl) * 64 + tl;
      wsp[o] = hi;
      wsp[o + 1048576] = lo;
      ext[o] = wraw;                                 // raw f32, [E][H][D]
    }
  } else {
    const u32 g = (blockIdx.x - 256) * 256u + threadIdx.x;
#if JAX_PARTITIONABLE
    u32 o0, o1;
    tf2x32(bk0, bk1, 0u, g, &o0, &o1);
    const u32 bits = o0 ^ o1;
    const float r = rates[g & 16383u];
    const float u = __uint_as_float((bits >> 9) | 0x3f800000u) - 1.0f;
    spk[g] = (u < r) ? (u16)0x3F80 : (u16)0;
#else
    u32 o0, o1;
    tf2x32(bk0, bk1, g, g + 163840u, &o0, &o1);
    const float r = rates[g & 16383u];
    const float ua = __uint_as_float((o0 >> 9) | 0x3f800000u) - 1.0f;
    const float ub = __uint_as_float((o1 >> 9) | 0x3f800000u) - 1.0f;
    spk[g] = (ua < r) ? (u16)0x3F80 : (u16)0;
    spk[g + 163840u] = (ub < r) ? (u16)0x3F80 : (u16)0;
#endif
  }
}

// ---------- K2: approx LIF scan, MFMA + flags (wave-aggregated append) ------
// R6 pathology: ~84k per-lane same-address return-atomics serialized ~80us.
// Now: popcount + 64-lane shfl prefix -> ONE atomicAdd per wave -> scatter.
// t-loop numerics identical to R5/R6 (verified passing).
__global__ __launch_bounds__(256, 3) void k_lif(
    const u16* __restrict__ spk, const u16* __restrict__ wsp,
    u8* __restrict__ cnt, u32* __restrict__ fcnt, u32* __restrict__ flist)
{
  const int hblk = blockIdx.x, bblk = blockIdx.y, e = blockIdx.z;
  const int tid = threadIdx.x;
  const int w = tid >> 6, lane = tid & 63;
  const int wb = w & 1, wh = w >> 1;
  const int lr = lane & 15, lg = lane >> 4;
  const int b0 = bblk * 32 + wb * 16;
  const int h0 = hblk * 128 + wh * 64;

  // B frags: wsp[s][e][h][d]; lane: n = lr (h), k = kc*32 + lg*8 + j
  bf16x8 bf[4][2][2];
#pragma unroll
  for (int nt = 0; nt < 4; ++nt)
#pragma unroll
    for (int kc = 0; kc < 2; ++kc)
#pragma unroll
      for (int s = 0; s < 2; ++s)
        bf[nt][kc][s] = *(const bf16x8*)(wsp +
            ((size_t)((s * 16 + e) * 1024 + h0 + nt * 16 + lr)) * 64 + kc * 32 + lg * 8);
#pragma unroll
  for (int nt = 0; nt < 4; ++nt)
#pragma unroll
    for (int kc = 0; kc < 2; ++kc)
#pragma unroll
      for (int s = 0; s < 2; ++s)
        asm volatile("" : "+v"(bf[nt][kc][s]));

  f32x4 v[4];
  int cn[4][4];
  u32 fl = 0;
#pragma unroll
  for (int nt = 0; nt < 4; ++nt) {
    v[nt] = (f32x4){0.f, 0.f, 0.f, 0.f};
#pragma unroll
    for (int i = 0; i < 4; ++i) cn[nt][i] = 0;
  }

  const u16* abase = spk + (size_t)(b0 + lr) * 64 + lg * 8;
  bf16x8 a0 = *(const bf16x8*)(abase);
  bf16x8 a1 = *(const bf16x8*)(abase + 32);

#define PROC(VAL, CREF, BIT) {                                  \
    const float tt = (VAL) - 0.5f;                              \
    if (__builtin_fabsf(tt) < FLAG_DELTA) fl |= (1u << (BIT));  \
    const bool sp = (tt >= 0.f);                                \
    (CREF) += sp;                                               \
    (VAL) = sp ? 0.f : (VAL); }

  for (int t = 0; t < 20; ++t) {
    const int tn = (t < 19) ? t + 1 : 19;          // prefetch next (clamped)
    const bf16x8 n0 = *(const bf16x8*)(abase + (size_t)tn * 16384);
    const bf16x8 n1 = *(const bf16x8*)(abase + (size_t)tn * 16384 + 32);
#pragma unroll
    for (int nt = 0; nt < 4; ++nt) {
      f32x4 accA = v[nt] * 0.95f;                  // hi chain, seeded v*(1-leak)
      accA = __builtin_amdgcn_mfma_f32_16x16x32_bf16(a0, bf[nt][0][0], accA, 0, 0, 0);
      accA = __builtin_amdgcn_mfma_f32_16x16x32_bf16(a1, bf[nt][1][0], accA, 0, 0, 0);
      f32x4 accB = (f32x4){0.f, 0.f, 0.f, 0.f};    // lo chain (tiny terms)
      accB = __builtin_amdgcn_mfma_f32_16x16x32_bf16(a0, bf[nt][0][1], accB, 0, 0, 0);
      accB = __builtin_amdgcn_mfma_f32_16x16x32_bf16(a1, bf[nt][1][1], accB, 0, 0, 0);
      f32x4 nv = accA + accB;                      // merge (4 v_add)
      PROC(nv.x, cn[nt][0], nt * 4 + 0)
      PROC(nv.y, cn[nt][1], nt * 4 + 1)
      PROC(nv.z, cn[nt][2], nt * 4 + 2)
      PROC(nv.w, cn[nt][3], nt * 4 + 3)
      v[nt] = nv;
    }
    a0 = n0; a1 = n1;
  }
#undef PROC

  // C/D layout: col = lane&15 (h), row = (lane>>4)*4 + reg (b)
#pragma unroll
  for (int nt = 0; nt < 4; ++nt) {
    const int h = h0 + nt * 16 + lr;
#pragma unroll
    for (int i = 0; i < 4; ++i) {
      const int b = b0 + lg * 4 + i;
      cnt[((size_t)e * 256 + b) * 1024 + h] = (u8)cn[nt][i];
    }
  }

  // wave-aggregated flag append: <=1 atomic per wave
  const u32 myc = (u32)__builtin_popcount((int)fl);
  u32 pre = myc;
#pragma unroll
  for (int off = 1; off < 64; off <<= 1) {
    const u32 xx = __shfl_up(pre, off, 64);
    if (lane >= off) pre += xx;
  }
  const u32 tot = __shfl(pre, 63, 64);
  if (tot) {
    u32 base = 0;
    if (lane == 63) base = atomicAdd(fcnt, tot);
    base = __shfl(base, 63, 64);
    u32 slot = base + pre - myc;
    if (fl) {
#pragma unroll
      for (int nt = 0; nt < 4; ++nt)
#pragma unroll
        for (int i = 0; i < 4; ++i)
          if ((fl >> (nt * 4 + i)) & 1u) {
            if (slot < FLAG_CAP)
              flist[slot] = ((u32)e << 18) | ((u32)(b0 + lg * 4 + i) << 10) |
                            (u32)(h0 + nt * 16 + lr);
            slot++;
          }
    }
  }
}

// ---------- K2b: exact recompute of flagged elements (round-2 math) ---------
// weights now contiguous 256B per element via ext[E][H][D] (was 64 lines).
__global__ __launch_bounds__(256) void k_fix(
    const u16* __restrict__ spk, const float* __restrict__ ext,
    const u32* __restrict__ fcnt, const u32* __restrict__ flist,
    u8* __restrict__ cnt)
{
  u32 n = fcnt[0];
  if (n > FLAG_CAP) n = FLAG_CAP;
  for (u32 i = blockIdx.x * 256u + threadIdx.x; i < n; i += 65536u) {
    const u32 p = flist[i];
    const int h = (int)(p & 1023u), b = (int)((p >> 10) & 255u), e = (int)(p >> 18);
    const float* __restrict__ wbp = ext + ((size_t)e * 1024 + h) * 64;
    float wr[64];
#pragma unroll
    for (int d = 0; d < 64; ++d) wr[d] = wbp[d];
    float v = 0.f;
    int c = 0;
    for (int t = 0; t < 20; ++t) {
      const uint4* __restrict__ sr = (const uint4*)(spk + (size_t)(t * 256 + b) * 64);
      float cc = 0.f;
#pragma unroll
      for (int w8 = 0; w8 < 8; ++w8) {
        const uint4 sv = sr[w8];
        cc = __builtin_fmaf(__uint_as_float(sv.x << 16),         wr[w8 * 8 + 0], cc);
        cc = __builtin_fmaf(__uint_as_float(sv.x & 0xFFFF0000u), wr[w8 * 8 + 1], cc);
        cc = __builtin_fmaf(__uint_as_float(sv.y << 16),         wr[w8 * 8 + 2], cc);
        cc = __builtin_fmaf(__uint_as_float(sv.y & 0xFFFF0000u), wr[w8 * 8 + 3], cc);
        cc = __builtin_fmaf(__uint_as_float(sv.z << 16),         wr[w8 * 8 + 4], cc);
        cc = __builtin_fmaf(__uint_as_float(sv.z & 0xFFFF0000u), wr[w8 * 8 + 5], cc);
        cc = __builtin_fmaf(__uint_as_float(sv.w << 16),         wr[w8 * 8 + 6], cc);
        cc = __builtin_fmaf(__uint_as_float(sv.w & 0xFFFF0000u), wr[w8 * 8 + 7], cc);
      }
      const float nv = __fadd_rn(v, __fmul_rn(__fsub_rn(cc, v), 0.05f));
      if (nv >= 0.5f) { c++; v = 0.f; } else v = nv;
    }
    cnt[((size_t)e * 256 + b) * 1024 + h] = (u8)c;
  }
}

// ---------- K3: out[b,h] = ascending-e fma chain of (cnt/20)*p --------------
__global__ __launch_bounds__(256) void k_combine(
    const u8* __restrict__ cnt, const float* __restrict__ gateo,
    float* __restrict__ out)
{
  const int idx = blockIdx.x * 256 + threadIdx.x;
  const int b = idx >> 10, h = idx & 1023;
  float s = 0.f;
#pragma unroll
  for (int e = 0; e < 16; ++e) {
    const float av = __fdiv_rn((float)cnt[((size_t)e * 256 + b) * 1024 + h], 20.f);
    s = __builtin_fmaf(av, gateo[b * 16 + e], s);
  }
  out[idx] = s;
}

// ---------- launch ----------------------------------------------------------
extern "C" void kernel_launch(void* const* d_in, const int* in_sizes, int n_in,
                              void* d_out, int out_size, void* d_ws, size_t ws_size,
                              hipStream_t stream)
{
  (void)in_sizes; (void)n_in; (void)out_size; (void)ws_size;
  const float* q     = (const float*)d_in[0];
  const float* gbias = (const float*)d_in[1];
  const float* temp  = (const float*)d_in[2];
  const float* win   = (const float*)d_in[3];
  const float* ex    = (const float*)d_in[4];
  const float* gk    = (const float*)d_in[5];
  float* out = (float*)d_out;

  char* ws = (char*)d_ws;
  u16*  spk   = (u16*)(ws + 0);            // [20][256][64] bf16    655360 B
  float* rates = (float*)(ws + 655360);    // [256][64] f32          65536 B
  float* gateo = (float*)(ws + 720896);    // [256][16] f32          16384 B
  u16*  wsp   = (u16*)(ws + 737280);       // [2][16][1024][64]    4194304 B
  u8*   cnt   = (u8*)(ws + 4931584);       // [16][256][1024] u8   4194304 B
  u32*  fcnt  = (u32*)(ws + 9125888);      // counter                  4 B
  u32*  flist = (u32*)(ws + 9126912);      // [262144] u32         1048576 B
  float* ext  = (float*)(ws + 10175488);   // [16][1024][64] f32   4194304 B
                                           // total: 14369792 B

  u32 bk0, bk1;
#if JAX_PARTITIONABLE
  tf2x32(0u, 0u, 0u, 1u, &bk0, &bk1);
#else
  u32 a0o, a1o, b0o, b1o;
  tf2x32(0u, 0u, 0u, 2u, &a0o, &a1o);
  tf2x32(0u, 0u, 1u, 3u, &b0o, &b1o);
  bk0 = a1o; bk1 = b1o;
#endif

  k_gate<<<256, 64, 0, stream>>>(q, win, gbias, temp, gk, rates, gateo, fcnt);
#if JAX_PARTITIONABLE
  k_prep<<<256 + 1280, 256, 0, stream>>>(ex, wsp, ext, rates, spk, bk0, bk1);
#else
  k_prep<<<256 + 640, 256, 0, stream>>>(ex, wsp, ext, rates, spk, bk0, bk1);
#endif
  k_lif<<<dim3(8, 8, 16), 256, 0, stream>>>(spk, wsp, cnt, fcnt, flist);
  k_fix<<<256, 256, 0, stream>>>(spk, ext, fcnt, flist, cnt);
  k_combine<<<1024, 256, 0, stream>>>(cnt, gateo, out);
}